// Round 2
// baseline (6751.881 us; speedup 1.0000x reference)
//
#include <hip/hip_runtime.h>

// SimpleRNN: h_{t+1} = tanh(h Wh^T + x_t Wx^T + b), return h_1024.
// SEQ=1024, NB=64, HID=512, IN=512. W is [512][1024] = [Wh | Wx]. All fp32 I/O.
//
// Phase 1 (prepass): U[t][b][j] = x_t[b]·Wx[j] + b[j] as one MFMA f16 GEMM,
//   U stored f16 in ws (64 MiB).
// Phase 2 (recurrent): 256 WGs = 64 batches x 4 row-slices. Each WG pins its
//   128x512 slice of Wh as f16 half2 in VGPRs (128 regs/thread, enforced by
//   asm barrier — R1 showed the compiler otherwise sinks the W loads into the
//   t-loop: VGPR_Count=96, 256 scalar refetches/thread/step, 6.4 us/step).

#define SEQ 1024
#define NB  64
#define HID 512

typedef _Float16 half2v __attribute__((ext_vector_type(2)));
typedef _Float16 f16x8  __attribute__((ext_vector_type(8)));
typedef float    f32x4  __attribute__((ext_vector_type(4)));

#if __has_builtin(__builtin_amdgcn_fdot2)
#define DOT2(a, b, c) __builtin_amdgcn_fdot2((a), (b), (c), false)
#else
static __device__ __forceinline__ float DOT2(half2v a, half2v b, float c) {
  return c + (float)a.x * (float)b.x + (float)a.y * (float)b.y;
}
#endif

// ---------------------------------------------------------------- prepass ---
__global__ __launch_bounds__(256, 2)
void rnn_prepass(const float* __restrict__ X, const float* __restrict__ W,
                 const float* __restrict__ bias, _Float16* __restrict__ U) {
  __shared__ __align__(16) _Float16 As[128][40];  // +8 pad: bank-friendly
  __shared__ __align__(16) _Float16 Bs[128][40];
  const int tid = threadIdx.x;
  const int m0 = blockIdx.x * 128;   // 512 m-tiles
  const int n0 = blockIdx.y * 128;   // 4 n-tiles
  const int wave = tid >> 6, lane = tid & 63;
  const int wm = (wave >> 1) * 64, wn = (wave & 1) * 64;  // 2x2 wave grid
  const int l15 = lane & 15, q = lane >> 4;

  f32x4 acc[4][4];
#pragma unroll
  for (int i = 0; i < 4; ++i)
#pragma unroll
    for (int j = 0; j < 4; ++j) acc[i][j] = (f32x4){0.f, 0.f, 0.f, 0.f};

  const int srow = tid >> 1;
  const int shalf = (tid & 1) * 16;

  for (int k0 = 0; k0 < 512; k0 += 32) {
    const float* asrc = X + (size_t)(m0 + srow) * 512 + k0 + shalf;
    const float* bsrc = W + (size_t)(n0 + srow) * 1024 + 512 + k0 + shalf;
    float4 a0 = *(const float4*)(asrc);
    float4 a1 = *(const float4*)(asrc + 4);
    float4 a2 = *(const float4*)(asrc + 8);
    float4 a3 = *(const float4*)(asrc + 12);
    float4 b0 = *(const float4*)(bsrc);
    float4 b1 = *(const float4*)(bsrc + 4);
    float4 b2 = *(const float4*)(bsrc + 8);
    float4 b3 = *(const float4*)(bsrc + 12);
    __syncthreads();  // previous iter's frag reads done before LDS overwrite
    f16x8 pa0 = {(_Float16)a0.x, (_Float16)a0.y, (_Float16)a0.z, (_Float16)a0.w,
                 (_Float16)a1.x, (_Float16)a1.y, (_Float16)a1.z, (_Float16)a1.w};
    f16x8 pa1 = {(_Float16)a2.x, (_Float16)a2.y, (_Float16)a2.z, (_Float16)a2.w,
                 (_Float16)a3.x, (_Float16)a3.y, (_Float16)a3.z, (_Float16)a3.w};
    f16x8 pb0 = {(_Float16)b0.x, (_Float16)b0.y, (_Float16)b0.z, (_Float16)b0.w,
                 (_Float16)b1.x, (_Float16)b1.y, (_Float16)b1.z, (_Float16)b1.w};
    f16x8 pb1 = {(_Float16)b2.x, (_Float16)b2.y, (_Float16)b2.z, (_Float16)b2.w,
                 (_Float16)b3.x, (_Float16)b3.y, (_Float16)b3.z, (_Float16)b3.w};
    *(f16x8*)&As[srow][shalf] = pa0;
    *(f16x8*)&As[srow][shalf + 8] = pa1;
    *(f16x8*)&Bs[srow][shalf] = pb0;
    *(f16x8*)&Bs[srow][shalf + 8] = pb1;
    __syncthreads();
    f16x8 av[4], bv[4];
#pragma unroll
    for (int i = 0; i < 4; ++i)
      av[i] = *(const f16x8*)&As[wm + i * 16 + l15][q * 8];
#pragma unroll
    for (int j = 0; j < 4; ++j)
      bv[j] = *(const f16x8*)&Bs[wn + j * 16 + l15][q * 8];
#pragma unroll
    for (int i = 0; i < 4; ++i)
#pragma unroll
      for (int j = 0; j < 4; ++j)
        acc[i][j] = __builtin_amdgcn_mfma_f32_16x16x32_f16(av[i], bv[j], acc[i][j], 0, 0, 0);
  }
  float bj[4];
#pragma unroll
  for (int j = 0; j < 4; ++j) bj[j] = bias[n0 + wn + j * 16 + l15];
#pragma unroll
  for (int i = 0; i < 4; ++i)
#pragma unroll
    for (int j = 0; j < 4; ++j)
#pragma unroll
      for (int r = 0; r < 4; ++r) {
        // C/D layout: col = lane&15, row = (lane>>4)*4 + reg  [m89/m91]
        int m = m0 + wm + i * 16 + q * 4 + r;
        int n = n0 + wn + j * 16 + l15;
        U[(size_t)m * 512 + n] = (_Float16)(acc[i][j][r] + bj[j]);
      }
}

// -------------------------------------------------------------- recurrent ---
__global__ __launch_bounds__(256, 1)
void rnn_recur(const float* __restrict__ W, const _Float16* __restrict__ U,
               unsigned int* hbuf, int* flags, float* __restrict__ out) {
  const int blk = blockIdx.x;
  const int batch = blk & 63;
  const int g = blk >> 6;      // row-slice 0..3 (rows 128g..128g+127)
  const int tid = threadIdx.x;
  const int rg = tid & 31;     // row group (4 rows each)
  const int c = tid >> 5;      // k-chunk 0..7 (64 k's each)

  __shared__ half2v hlds[256];       // h_t as 512 f16
  __shared__ float part[128][9];     // partial sums, padded stride

  // Wh slice -> registers: rows 128g + rg*4 + i, cols [64c, 64c+64)
  // Loaded ONCE (float4-vectorized), packed to f16, then pinned with an asm
  // optimization barrier so the compiler cannot sink the loads into the loop.
  half2v wreg[4][32];
#pragma unroll
  for (int i = 0; i < 4; ++i) {
    const float* wrow = W + (size_t)(128 * g + rg * 4 + i) * 1024 + c * 64;
#pragma unroll
    for (int kk = 0; kk < 8; ++kk) {
      float4 w4a = *(const float4*)(wrow + 8 * kk);
      float4 w4b = *(const float4*)(wrow + 8 * kk + 4);
      half2v p0, p1, p2, p3;
      p0.x = (_Float16)w4a.x; p0.y = (_Float16)w4a.y;
      p1.x = (_Float16)w4a.z; p1.y = (_Float16)w4a.w;
      p2.x = (_Float16)w4b.x; p2.y = (_Float16)w4b.y;
      p3.x = (_Float16)w4b.z; p3.y = (_Float16)w4b.w;
      wreg[i][4 * kk + 0] = p0;
      wreg[i][4 * kk + 1] = p1;
      wreg[i][4 * kk + 2] = p2;
      wreg[i][4 * kk + 3] = p3;
    }
  }
#pragma unroll
  for (int i = 0; i < 4; ++i)
#pragma unroll
    for (int kk = 0; kk < 32; ++kk)
      asm volatile("" : "+v"(wreg[i][kk]));  // pin: value now opaque, must stay live

  const unsigned int* ubase = (const unsigned int*)U;
  int* myflag = flags + ((size_t)batch * 4 + g) * 32;

  float h0f = 0.f, h1f = 0.f;
  for (int t = 0; t < SEQ; ++t) {
    // prefetch this step's U half2 (independent of sync)
    unsigned int ubits = 0;
    if (tid < 64)
      ubits = ubase[((size_t)t * NB + batch) * 256 + g * 64 + tid];
    // wait for all 4 slices of h_t to be published
    if (tid < 4) {
      const int* f = flags + ((size_t)batch * 4 + tid) * 32;
      while (__hip_atomic_load(f, __ATOMIC_ACQUIRE, __HIP_MEMORY_SCOPE_AGENT) < t)
        __builtin_amdgcn_s_sleep(1);
    }
    __syncthreads();
    // stage h_t (agent-scope loads: bypass stale cache lines from step t-2)
    {
      unsigned int hb = __hip_atomic_load(
          hbuf + (size_t)(t & 1) * (NB * 256) + batch * 256 + tid,
          __ATOMIC_RELAXED, __HIP_MEMORY_SCOPE_AGENT);
      hlds[tid] = __builtin_bit_cast(half2v, hb);
    }
    __syncthreads();
    // 4 rows x 64 k of dot products per thread (128 v_dot2_f32_f16)
    float a0 = 0.f, a1 = 0.f, a2 = 0.f, a3 = 0.f;
    const half2v* hp = &hlds[c * 32];
#pragma unroll
    for (int kk = 0; kk < 32; ++kk) {
      half2v hv = hp[kk];
      a0 = DOT2(wreg[0][kk], hv, a0);
      a1 = DOT2(wreg[1][kk], hv, a1);
      a2 = DOT2(wreg[2][kk], hv, a2);
      a3 = DOT2(wreg[3][kk], hv, a3);
    }
    part[rg * 4 + 0][c] = a0;
    part[rg * 4 + 1][c] = a1;
    part[rg * 4 + 2][c] = a2;
    part[rg * 4 + 3][c] = a3;
    __syncthreads();
    if (tid < 64) {
      float s0 = 0.f, s1 = 0.f;
#pragma unroll
      for (int cc = 0; cc < 8; ++cc) {
        s0 += part[2 * tid][cc];
        s1 += part[2 * tid + 1][cc];
      }
      half2v uh = __builtin_bit_cast(half2v, ubits);
      h0f = tanhf(s0 + (float)uh.x);
      h1f = tanhf(s1 + (float)uh.y);
      half2v hh;
      hh.x = (_Float16)h0f;
      hh.y = (_Float16)h1f;
      __hip_atomic_store(
          hbuf + (size_t)((t + 1) & 1) * (NB * 256) + batch * 256 + g * 64 + tid,
          __builtin_bit_cast(unsigned int, hh),
          __ATOMIC_RELAXED, __HIP_MEMORY_SCOPE_AGENT);
    }
    __syncthreads();  // all slice stores drained before flag
    if (tid == 0)
      __hip_atomic_store(myflag, t + 1, __ATOMIC_RELEASE, __HIP_MEMORY_SCOPE_AGENT);
  }
  if (tid < 64) {
    out[(size_t)batch * HID + 128 * g + 2 * tid] = h0f;
    out[(size_t)batch * HID + 128 * g + 2 * tid + 1] = h1f;
  }
}

// ------------------------------------------------------------------- host ---
extern "C" void kernel_launch(void* const* d_in, const int* in_sizes, int n_in,
                              void* d_out, int out_size, void* d_ws, size_t ws_size,
                              hipStream_t stream) {
  const float* X    = (const float*)d_in[0];  // [1024][64][512]
  const float* W    = (const float*)d_in[1];  // [512][1024]
  const float* bias = (const float*)d_in[2];  // [512]
  float* out = (float*)d_out;                 // [64][512]

  // ws layout: U f16 (64 MiB) | hbuf u32[2][64][256] (128 KiB) | flags (32 KiB)
  char* ws = (char*)d_ws;
  _Float16* U = (_Float16*)ws;
  unsigned int* hbuf = (unsigned int*)(ws + (size_t)SEQ * NB * HID * 2);
  int* flags = (int*)(ws + (size_t)SEQ * NB * HID * 2 + (size_t)2 * NB * 256 * 4);

  // h_0 = 0 (parity-0 buffer) and step flags = 0; ws is poisoned each call
  hipMemsetAsync(hbuf, 0, NB * 256 * 4, stream);
  hipMemsetAsync(flags, 0, NB * 4 * 32 * 4, stream);

  rnn_prepass<<<dim3(512, 4), dim3(256), 0, stream>>>(X, W, bias, U);

  const float* Wp = W;
  const _Float16* Up = U;
  unsigned int* hb = hbuf;
  int* fl = flags;
  float* op = out;
  void* args[] = {(void*)&Wp, (void*)&Up, (void*)&hb, (void*)&fl, (void*)&op};
  // cooperative launch: guarantees all 256 spinning WGs are co-resident
  hipError_t e = hipLaunchCooperativeKernel(
      reinterpret_cast<void*>(rnn_recur), dim3(256), dim3(256), args, 0, stream);
  if (e != hipSuccess) {
    rnn_recur<<<dim3(256), dim3(256), 0, stream>>>(Wp, Up, hb, fl, op);
  }
}

// Round 3
// 1586.301 us; speedup vs baseline: 4.2564x; 4.2564x over previous
//
#include <hip/hip_runtime.h>

// SimpleRNN: h_{t+1} = tanh(h Wh^T + x_t Wx^T + b), return h_1024.
// SEQ=1024, NB=64, HID=512, IN=512. W is [512][1024] = [Wh | Wx]. All fp32 I/O.
//
// Phase 1 (prepass): U[t][b][j] = x_t[b]·Wx[j] + b[j] as MFMA f16 GEMM, U f16 in ws.
// Phase 2 (recurrent): 256 WGs = 64 batches x 4 row-slices. Each WG stages its
//   128x512 Wh slice into LDS as f16 (128 KB, thread-order layout so per-step
//   reads are lane-consecutive ds_read_b128 — conflict-free). R1/R2 showed the
//   compiler refuses to keep the slice in VGPRs (VGPR_Count pinned at 96, W
//   refetched from L2 every step -> 6.4 us/step); LDS residency is enforceable.
// Sync: h published as atomic u64 {tag, 2xf16} into a parity ping-pong buffer;
//   consumers poll the data word itself (no separate flag, no release fence).

#define SEQ 1024
#define NB  64
#define HID 512

typedef _Float16 half2v __attribute__((ext_vector_type(2)));
typedef _Float16 f16x8  __attribute__((ext_vector_type(8)));
typedef float    f32x4  __attribute__((ext_vector_type(4)));

#if __has_builtin(__builtin_amdgcn_fdot2)
#define DOT2(a, b, c) __builtin_amdgcn_fdot2((a), (b), (c), false)
#else
static __device__ __forceinline__ float DOT2(half2v a, half2v b, float c) {
  return c + (float)a.x * (float)b.x + (float)a.y * (float)b.y;
}
#endif

static __device__ __forceinline__ float fast_tanh(float x) {
  // tanh(x) = (e^{2x}-1)/(e^{2x}+1); __expf -> v_exp_f32, err << f16 quantization
  float e = __expf(2.0f * x);
  return (e - 1.0f) / (e + 1.0f);
}

// ---------------------------------------------------------------- prepass ---
__global__ __launch_bounds__(256, 2)
void rnn_prepass(const float* __restrict__ X, const float* __restrict__ W,
                 const float* __restrict__ bias, _Float16* __restrict__ U) {
  __shared__ __align__(16) _Float16 As[128][40];  // +8 pad: bank-friendly
  __shared__ __align__(16) _Float16 Bs[128][40];
  const int tid = threadIdx.x;
  const int m0 = blockIdx.x * 128;   // 512 m-tiles
  const int n0 = blockIdx.y * 128;   // 4 n-tiles
  const int wave = tid >> 6, lane = tid & 63;
  const int wm = (wave >> 1) * 64, wn = (wave & 1) * 64;  // 2x2 wave grid
  const int l15 = lane & 15, q = lane >> 4;

  f32x4 acc[4][4];
#pragma unroll
  for (int i = 0; i < 4; ++i)
#pragma unroll
    for (int j = 0; j < 4; ++j) acc[i][j] = (f32x4){0.f, 0.f, 0.f, 0.f};

  const int srow = tid >> 1;
  const int shalf = (tid & 1) * 16;

  for (int k0 = 0; k0 < 512; k0 += 32) {
    const float* asrc = X + (size_t)(m0 + srow) * 512 + k0 + shalf;
    const float* bsrc = W + (size_t)(n0 + srow) * 1024 + 512 + k0 + shalf;
    float4 a0 = *(const float4*)(asrc);
    float4 a1 = *(const float4*)(asrc + 4);
    float4 a2 = *(const float4*)(asrc + 8);
    float4 a3 = *(const float4*)(asrc + 12);
    float4 b0 = *(const float4*)(bsrc);
    float4 b1 = *(const float4*)(bsrc + 4);
    float4 b2 = *(const float4*)(bsrc + 8);
    float4 b3 = *(const float4*)(bsrc + 12);
    __syncthreads();  // previous iter's frag reads done before LDS overwrite
    f16x8 pa0 = {(_Float16)a0.x, (_Float16)a0.y, (_Float16)a0.z, (_Float16)a0.w,
                 (_Float16)a1.x, (_Float16)a1.y, (_Float16)a1.z, (_Float16)a1.w};
    f16x8 pa1 = {(_Float16)a2.x, (_Float16)a2.y, (_Float16)a2.z, (_Float16)a2.w,
                 (_Float16)a3.x, (_Float16)a3.y, (_Float16)a3.z, (_Float16)a3.w};
    f16x8 pb0 = {(_Float16)b0.x, (_Float16)b0.y, (_Float16)b0.z, (_Float16)b0.w,
                 (_Float16)b1.x, (_Float16)b1.y, (_Float16)b1.z, (_Float16)b1.w};
    f16x8 pb1 = {(_Float16)b2.x, (_Float16)b2.y, (_Float16)b2.z, (_Float16)b2.w,
                 (_Float16)b3.x, (_Float16)b3.y, (_Float16)b3.z, (_Float16)b3.w};
    *(f16x8*)&As[srow][shalf] = pa0;
    *(f16x8*)&As[srow][shalf + 8] = pa1;
    *(f16x8*)&Bs[srow][shalf] = pb0;
    *(f16x8*)&Bs[srow][shalf + 8] = pb1;
    __syncthreads();
    f16x8 av[4], bv[4];
#pragma unroll
    for (int i = 0; i < 4; ++i)
      av[i] = *(const f16x8*)&As[wm + i * 16 + l15][q * 8];
#pragma unroll
    for (int j = 0; j < 4; ++j)
      bv[j] = *(const f16x8*)&Bs[wn + j * 16 + l15][q * 8];
#pragma unroll
    for (int i = 0; i < 4; ++i)
#pragma unroll
      for (int j = 0; j < 4; ++j)
        acc[i][j] = __builtin_amdgcn_mfma_f32_16x16x32_f16(av[i], bv[j], acc[i][j], 0, 0, 0);
  }
  float bj[4];
#pragma unroll
  for (int j = 0; j < 4; ++j) bj[j] = bias[n0 + wn + j * 16 + l15];
#pragma unroll
  for (int i = 0; i < 4; ++i)
#pragma unroll
    for (int j = 0; j < 4; ++j)
#pragma unroll
      for (int r = 0; r < 4; ++r) {
        // C/D layout: col = lane&15, row = (lane>>4)*4 + reg  [m89/m91]
        int m = m0 + wm + i * 16 + q * 4 + r;
        int n = n0 + wn + j * 16 + l15;
        U[(size_t)m * 512 + n] = (_Float16)(acc[i][j][r] + bj[j]);
      }
}

// -------------------------------------------------------------- recurrent ---
__global__ __launch_bounds__(256, 1)
void rnn_recur(const float* __restrict__ W, const _Float16* __restrict__ U,
               unsigned long long* hbuf, float* __restrict__ out) {
  const int blk = blockIdx.x;
  const int batch = blk & 63;
  const int g = blk >> 6;      // row-slice 0..3 (rows 128g..128g+127)
  const int tid = threadIdx.x;
  const int rg = tid & 31;     // row group (4 local rows: rg*4+i)
  const int c = tid >> 5;      // k-chunk 0..7 (64 k's each)

  // LDS: weights in thread-order chunks -> per-step reads are ds_read_b128
  // with 16 B lane stride (2 lanes/bank = free). 128 KB + 1 KB + 4.5 KB.
  __shared__ __align__(16) f16x8 wlds[32][256];  // [chunk i*8+qq][tid]
  __shared__ half2v hlds[256];                   // h_t as 256 x (2xf16)
  __shared__ float part[128][9];                 // partial sums, padded

  // One-time: load 4 rows x 64 cols of Wh, convert f16, store own chunks.
  {
#pragma unroll
    for (int i = 0; i < 4; ++i) {
      const float* wrow = W + (size_t)(128 * g + rg * 4 + i) * 1024 + c * 64;
#pragma unroll
      for (int qq = 0; qq < 8; ++qq) {
        float4 wa = *(const float4*)(wrow + 8 * qq);
        float4 wb = *(const float4*)(wrow + 8 * qq + 4);
        f16x8 p = {(_Float16)wa.x, (_Float16)wa.y, (_Float16)wa.z, (_Float16)wa.w,
                   (_Float16)wb.x, (_Float16)wb.y, (_Float16)wb.z, (_Float16)wb.w};
        wlds[i * 8 + qq][tid] = p;
      }
    }
  }
  __syncthreads();

  const unsigned int* ubase = (const unsigned int*)U;
  unsigned long long* hb = hbuf + (size_t)batch * 256;      // parity stride NB*256
  unsigned long long* hpub = hb + (size_t)(NB * 256) * 0;   // computed per-step

  float h0f = 0.f, h1f = 0.f;
  for (int t = 0; t < SEQ; ++t) {
    // prefetch this step's U half2 (independent of sync)
    unsigned int ubits = 0;
    if (tid < 64)
      ubits = ubase[((size_t)t * NB + batch) * 256 + g * 64 + tid];

    // poll my h-pair for tag t (parity t&1); tag+data are one atomic u64
    {
      const unsigned long long* src =
          hb + (size_t)(t & 1) * (NB * 256) + tid;
      unsigned long long e;
      do {
        e = __hip_atomic_load(src, __ATOMIC_RELAXED, __HIP_MEMORY_SCOPE_AGENT);
      } while ((unsigned int)(e >> 32) != (unsigned int)t);
      hlds[tid] = __builtin_bit_cast(half2v, (unsigned int)e);
    }
    __syncthreads();  // SYNC1: h_t staged; also fences part[] reuse (see below)

    // 4 local rows x 64 k per thread: 32 ds_read_b128 + 128 v_dot2_f32_f16
    float a0 = 0.f, a1 = 0.f, a2 = 0.f, a3 = 0.f;
    const half2v* hp = &hlds[c * 32];
#pragma unroll
    for (int qq = 0; qq < 8; ++qq) {
      half2v hv0 = hp[qq * 4 + 0];
      half2v hv1 = hp[qq * 4 + 1];
      half2v hv2 = hp[qq * 4 + 2];
      half2v hv3 = hp[qq * 4 + 3];
#pragma unroll
      for (int i = 0; i < 4; ++i) {
        f16x8 wv = wlds[i * 8 + qq][tid];
        half2v w0 = {wv[0], wv[1]};
        half2v w1 = {wv[2], wv[3]};
        half2v w2 = {wv[4], wv[5]};
        half2v w3 = {wv[6], wv[7]};
        float* ai = (i == 0) ? &a0 : (i == 1) ? &a1 : (i == 2) ? &a2 : &a3;
        *ai = DOT2(w0, hv0, *ai);
        *ai = DOT2(w1, hv1, *ai);
        *ai = DOT2(w2, hv2, *ai);
        *ai = DOT2(w3, hv3, *ai);
      }
    }
    part[rg * 4 + 0][c] = a0;
    part[rg * 4 + 1][c] = a1;
    part[rg * 4 + 2][c] = a2;
    part[rg * 4 + 3][c] = a3;
    __syncthreads();  // SYNC2: partials visible

    if (tid < 64) {
      float s0 = 0.f, s1 = 0.f;
#pragma unroll
      for (int cc = 0; cc < 8; ++cc) {
        s0 += part[2 * tid][cc];
        s1 += part[2 * tid + 1][cc];
      }
      half2v uh = __builtin_bit_cast(half2v, ubits);
      h0f = fast_tanh(s0 + (float)uh.x);
      h1f = fast_tanh(s1 + (float)uh.y);
      half2v hh;
      hh.x = (_Float16)h0f;
      hh.y = (_Float16)h1f;
      unsigned long long word =
          ((unsigned long long)(unsigned int)(t + 1) << 32) |
          (unsigned long long)__builtin_bit_cast(unsigned int, hh);
      // publish h_{t+1} slice: single atomic u64, parity (t+1)&1.
      // Overwrite of h_{t-1} is safe: all 4 slices' tag==t observed this step
      // implies every WG of this batch finished loading h_{t-1}.
      __hip_atomic_store(
          hb + (size_t)((t + 1) & 1) * (NB * 256) + g * 64 + tid, word,
          __ATOMIC_RELAXED, __HIP_MEMORY_SCOPE_AGENT);
    }
    // no third barrier needed: next iter's hlds/part writes are ordered behind
    // SYNC1(t+1), which publishers only reach after their part[] reads.
  }
  if (tid < 64) {
    out[(size_t)batch * HID + 128 * g + 2 * tid] = h0f;
    out[(size_t)batch * HID + 128 * g + 2 * tid + 1] = h1f;
  }
  (void)hpub;
}

// ------------------------------------------------------------------- host ---
extern "C" void kernel_launch(void* const* d_in, const int* in_sizes, int n_in,
                              void* d_out, int out_size, void* d_ws, size_t ws_size,
                              hipStream_t stream) {
  const float* X    = (const float*)d_in[0];  // [1024][64][512]
  const float* W    = (const float*)d_in[1];  // [512][1024]
  const float* bias = (const float*)d_in[2];  // [512]
  float* out = (float*)d_out;                 // [64][512]

  // ws layout: U f16 (64 MiB) | hbuf u64[2][64][256] (256 KiB)
  char* ws = (char*)d_ws;
  _Float16* U = (_Float16*)ws;
  unsigned long long* hbuf =
      (unsigned long long*)(ws + (size_t)SEQ * NB * HID * 2);

  // parity-0 buffer = h_0 = 0 with tag 0 (ws is re-poisoned 0xAA each call;
  // 0xAAAAAAAA can never equal a tag in [0,1024], so parity-1 needs no init)
  hipMemsetAsync(hbuf, 0, (size_t)NB * 256 * 8, stream);

  rnn_prepass<<<dim3(512, 4), dim3(256), 0, stream>>>(X, W, bias, U);

  const float* Wp = W;
  const _Float16* Up = U;
  unsigned long long* hb = hbuf;
  float* op = out;
  void* args[] = {(void*)&Wp, (void*)&Up, (void*)&hb, (void*)&op};
  // cooperative launch: all 256 spinning WGs co-resident (1 WG/CU, LDS-bound)
  hipError_t e = hipLaunchCooperativeKernel(
      reinterpret_cast<void*>(rnn_recur), dim3(256), dim3(256), args, 0, stream);
  if (e != hipSuccess) {
    rnn_recur<<<dim3(256), dim3(256), 0, stream>>>(Wp, Up, hb, op);
  }
}